// Round 2
// baseline (15313.275 us; speedup 1.0000x reference)
//
#include <hip/hip_runtime.h>

// Fused persistent RNN encoder, v2:
//   h_{t+1} = relu([x_t | h_t] @ W^T + b), W natural [1024][2048] bf16.
// One cooperative kernel, 256 blocks x 512 thr (8 waves = 4 spatial 64x64 x 2 kq).
// Per step: wait(h_t) -> h-GEMM (K=1024) -> reduce+epilogue -> arrive ->
//           x-GEMM for t+1 (K=1024, h-independent) OVERLAPS the barrier.
// Barrier: arrive = release fetch_add; wait = relaxed atomic LOAD spin (no RMW).
// cg = blockIdx&7 -> W col-slab (512 KB) stays resident in its XCD's L2.

typedef __bf16 bf16;
typedef __bf16 bf16x8 __attribute__((ext_vector_type(8)));
typedef __bf16 bf16x4 __attribute__((ext_vector_type(4)));
typedef float f32x4 __attribute__((ext_vector_type(4)));

#define B_N 4096
#define T_N 35
#define U_N 1024
#define K2 2048
#define XROW (T_N * U_N)

#define AS1CP(p) ((const __attribute__((address_space(1))) void*)(p))
#define AS3CP(p) ((__attribute__((address_space(3))) void*)(p))

// ---- pack W (1024 x 2048 fp32) -> Wb (1024 x 2048 bf16, same layout) ----
__global__ __launch_bounds__(256) void pack_w(const float* __restrict__ W,
                                              bf16* __restrict__ Wb) {
  int i = (blockIdx.x * 256 + threadIdx.x) * 4;  // over 1024*2048
  f32x4 a = *(const f32x4*)(W + i);
  bf16x4 v = { (bf16)a.x, (bf16)a.y, (bf16)a.z, (bf16)a.w };
  *(bf16x4*)(Wb + i) = v;
}

struct Ctx {
  int w, g, lq, lm, wm, wn, lrow8, clog, r0, c0, xrow, xc2;
};

// One K=1024 half-GEMM: acc += A @ Wb[c0..+128][kw..kw+1024]^T
// XPART: A = x rows (fp32, reg-staged fp32->bf16, T14 issue-early/write-late)
// !XPART: A = hin rows (bf16, global_load_lds direct)
template<bool XPART>
__device__ __forceinline__ void sub_gemm(
    f32x4 (&acc)[4][4], const float* __restrict__ xb,
    const bf16* __restrict__ hin, const bf16* __restrict__ Wb,
    bf16 (&smem)[2][2][8192], const Ctx& cx)
{
  const int kw = XPART ? 0 : 1024;

  // ---- prologue: stage kk=0 into buf 0 ----
#pragma unroll
  for (int r = 0; r < 2; ++r) {
    int nr = cx.w * 16 + r * 8;
    const bf16* gb = Wb + (size_t)(cx.c0 + nr + cx.lrow8) * K2 + kw + cx.clog * 8;
    __builtin_amdgcn_global_load_lds(AS1CP(gb), AS3CP(&smem[0][1][nr * 64]), 16, 0, 0);
  }
  if (XPART) {
    f32x4 f0 = *(const f32x4*)(xb);
    f32x4 f1 = *(const f32x4*)(xb + 4);
    f32x4 f2 = *(const f32x4*)(xb + 8);
    f32x4 f3 = *(const f32x4*)(xb + 12);
    bf16x8 v0 = { (bf16)f0.x, (bf16)f0.y, (bf16)f0.z, (bf16)f0.w,
                  (bf16)f1.x, (bf16)f1.y, (bf16)f1.z, (bf16)f1.w };
    bf16x8 v1 = { (bf16)f2.x, (bf16)f2.y, (bf16)f2.z, (bf16)f2.w,
                  (bf16)f3.x, (bf16)f3.y, (bf16)f3.z, (bf16)f3.w };
    *(bf16x8*)(&smem[0][0][cx.xrow * 64 + (((cx.xc2 << 1) ^ (cx.xrow & 7)) << 3)]) = v0;
    *(bf16x8*)(&smem[0][0][cx.xrow * 64 + ((((cx.xc2 << 1) | 1) ^ (cx.xrow & 7)) << 3)]) = v1;
  } else {
#pragma unroll
    for (int r = 0; r < 2; ++r) {
      int nr = cx.w * 16 + r * 8;
      const bf16* gh = hin + (size_t)(cx.r0 + nr + cx.lrow8) * U_N + cx.clog * 8;
      __builtin_amdgcn_global_load_lds(AS1CP(gh), AS3CP(&smem[0][0][nr * 64]), 16, 0, 0);
    }
  }
  __syncthreads();

  int cur = 0;
  for (int kk = 0; kk < 1024; kk += 64) {
    const int nkk = kk + 64;
    const bool has = nkk < 1024;
    const int nxt = cur ^ 1;

    f32x4 f0, f1, f2, f3;
    if (XPART && has) {  // T14: issue x loads early
      const float* gx = xb + nkk;
      f0 = *(const f32x4*)(gx);
      f1 = *(const f32x4*)(gx + 4);
      f2 = *(const f32x4*)(gx + 8);
      f3 = *(const f32x4*)(gx + 12);
    }
    if (has) {
#pragma unroll
      for (int r = 0; r < 2; ++r) {
        int nr = cx.w * 16 + r * 8;
        const bf16* gb = Wb + (size_t)(cx.c0 + nr + cx.lrow8) * K2 + kw + nkk + cx.clog * 8;
        __builtin_amdgcn_global_load_lds(AS1CP(gb), AS3CP(&smem[nxt][1][nr * 64]), 16, 0, 0);
      }
      if (!XPART) {
#pragma unroll
        for (int r = 0; r < 2; ++r) {
          int nr = cx.w * 16 + r * 8;
          const bf16* gh = hin + (size_t)(cx.r0 + nr + cx.lrow8) * U_N + nkk + cx.clog * 8;
          __builtin_amdgcn_global_load_lds(AS1CP(gh), AS3CP(&smem[nxt][0][nr * 64]), 16, 0, 0);
        }
      }
    }

    // compute buf cur: this wave's kq = g only (K-split across wave groups)
    {
      const bf16* As = &smem[cur][0][0];
      const bf16* Bs = &smem[cur][1][0];
      bf16x8 af[4], bfr[4];
#pragma unroll
      for (int mi = 0; mi < 4; ++mi) {
        int rr = cx.wm * 64 + mi * 16 + cx.lm;
        af[mi] = *(const bf16x8*)(As + rr * 64 + ((((cx.g << 2) + cx.lq) ^ (rr & 7)) << 3));
      }
#pragma unroll
      for (int ni = 0; ni < 4; ++ni) {
        int cc = cx.wn * 64 + ni * 16 + cx.lm;
        bfr[ni] = *(const bf16x8*)(Bs + cc * 64 + ((((cx.g << 2) + cx.lq) ^ (cc & 7)) << 3));
      }
#pragma unroll
      for (int mi = 0; mi < 4; ++mi)
#pragma unroll
        for (int ni = 0; ni < 4; ++ni)
          acc[mi][ni] = __builtin_amdgcn_mfma_f32_16x16x32_bf16(af[mi], bfr[ni],
                                                                acc[mi][ni], 0, 0, 0);
    }

    if (XPART && has) {  // T14: convert + LDS-write after MFMAs
      bf16x8 v0 = { (bf16)f0.x, (bf16)f0.y, (bf16)f0.z, (bf16)f0.w,
                    (bf16)f1.x, (bf16)f1.y, (bf16)f1.z, (bf16)f1.w };
      bf16x8 v1 = { (bf16)f2.x, (bf16)f2.y, (bf16)f2.z, (bf16)f2.w,
                    (bf16)f3.x, (bf16)f3.y, (bf16)f3.z, (bf16)f3.w };
      *(bf16x8*)(&smem[nxt][0][cx.xrow * 64 + (((cx.xc2 << 1) ^ (cx.xrow & 7)) << 3)]) = v0;
      *(bf16x8*)(&smem[nxt][0][cx.xrow * 64 + ((((cx.xc2 << 1) | 1) ^ (cx.xrow & 7)) << 3)]) = v1;
    }
    __syncthreads();
    cur = nxt;
  }
}

__global__ __launch_bounds__(512, 1) void rnn_fused(
    const float* __restrict__ x, const bf16* __restrict__ Wb,
    const float* __restrict__ bias, bf16* __restrict__ hA,
    bf16* __restrict__ hB, float* __restrict__ out,
    unsigned* __restrict__ bar, int t0, int t1)
{
  __shared__ __align__(16) bf16 smem[2][2][8192];  // [buf][A=0/B=1], 64 KB

  const int tid = threadIdx.x;
  const int w = tid >> 6, l = tid & 63;
  const int L = blockIdx.x;
  const int cg = L & 7;        // XCD-local col-group: W slab L2-resident
  const int rg = L >> 3;       // 0..31

  Ctx cx;
  cx.w = w;
  cx.r0 = rg << 7;
  cx.c0 = cg << 7;
  const int s = w & 3;         // spatial wave 2x2 over 128x128
  cx.g = w >> 2;               // kq K-split group
  cx.wm = s & 1; cx.wn = s >> 1;
  cx.lq = l >> 4; cx.lm = l & 15;
  cx.lrow8 = l >> 3;
  cx.clog = (l & 7) ^ cx.lrow8;
  cx.xrow = tid >> 2;          // x staging: 4 thr/row, 16 floats each
  cx.xc2 = tid & 3;

  const float* xrowp = x + (size_t)(cx.r0 + cx.xrow) * XROW + cx.xc2 * 16;

  float bv[4];
#pragma unroll
  for (int ni = 0; ni < 4; ++ni) bv[ni] = bias[cx.c0 + cx.wn * 64 + ni * 16 + cx.lm];

  f32x4 acc[4][4] = {};

  for (int t = t0; t < t1; ++t) {
    const bf16* hin = (t & 1) ? hB : hA;
    bf16* hout = (t & 1) ? hA : hB;

    if (t == t0) {  // first step of this launch: no overlapped x-part available
      sub_gemm<true>(acc, xrowp + (size_t)t * U_N, nullptr, Wb, smem, cx);
    }
    if (t > t0) {   // coop mode: wait until all blocks finished step t-1
      if (tid == 0) {
        const unsigned tgt = (unsigned)t * 256u;
        while (__hip_atomic_load(bar, __ATOMIC_ACQUIRE,
                                 __HIP_MEMORY_SCOPE_AGENT) < tgt)
          __builtin_amdgcn_s_sleep(8);
      }
      __syncthreads();
      __threadfence();  // acquire: h_t writes from other XCDs visible
    }
    if (t > 0) {    // h contribution (h_0 == 0 -> skipped at t=0)
      sub_gemm<false>(acc, nullptr, hin, Wb, smem, cx);
    }

    // ---- kq-reduce split across groups + epilogue ----
    float* red = (float*)&smem[0][0][0];  // 64 KB scratch (all buffers dead)
    {
      const int base = (cx.g == 1) ? 0 : 32;
      const int mlo = (cx.g == 1) ? 0 : 2;  // write the half the OTHER group finalizes
#pragma unroll
      for (int mi = 0; mi < 2; ++mi)
#pragma unroll
        for (int ni = 0; ni < 4; ++ni)
          *(f32x4*)(red + (size_t)(base + s * 8 + mi * 4 + ni) * 256 + l * 4) =
              acc[mlo + mi][ni];
    }
    __syncthreads();
    {
      const int base = (cx.g == 1) ? 32 : 0;
      const int mlo = (cx.g == 1) ? 2 : 0;  // the half this group finalizes
#pragma unroll
      for (int mi = 0; mi < 2; ++mi)
#pragma unroll
        for (int ni = 0; ni < 4; ++ni)
          acc[mlo + mi][ni] +=
              *(const f32x4*)(red + (size_t)(base + s * 8 + mi * 4 + ni) * 256 + l * 4);
#pragma unroll
      for (int ni = 0; ni < 4; ++ni) {
        int col = cx.c0 + cx.wn * 64 + ni * 16 + cx.lm;
#pragma unroll
        for (int mi = 0; mi < 2; ++mi) {
          int rbase = cx.r0 + cx.wm * 64 + (mlo + mi) * 16 + cx.lq * 4;
#pragma unroll
          for (int i = 0; i < 4; ++i) {
            float v = acc[mlo + mi][ni][i] + bv[ni];
            v = v > 0.f ? v : 0.f;
            hout[(size_t)(rbase + i) * U_N + col] = (bf16)v;
            if (t == T_N - 1) out[(size_t)(rbase + i) * U_N + col] = v;
          }
        }
      }
    }

    // ---- arrive, then overlap: x-part of step t+1 (h-independent) ----
    if (t + 1 < t1) {
      __syncthreads();  // epilogue writes + red reads done before reuse/arrive
      if (tid == 0) {
        __threadfence();  // release h_{t+1} writes
        __hip_atomic_fetch_add(bar, 1u, __ATOMIC_RELEASE, __HIP_MEMORY_SCOPE_AGENT);
      }
#pragma unroll
      for (int mi = 0; mi < 4; ++mi)
#pragma unroll
        for (int ni = 0; ni < 4; ++ni)
          acc[mi][ni] = f32x4{0.f, 0.f, 0.f, 0.f};
      sub_gemm<true>(acc, xrowp + (size_t)(t + 1) * U_N, nullptr, Wb, smem, cx);
    }
  }
}

extern "C" void kernel_launch(void* const* d_in, const int* in_sizes, int n_in,
                              void* d_out, int out_size, void* d_ws, size_t ws_size,
                              hipStream_t stream) {
  const float* x    = (const float*)d_in[0];
  const float* W    = (const float*)d_in[1];
  const float* bias = (const float*)d_in[2];
  float* out = (float*)d_out;

  char* ws = (char*)d_ws;
  bf16* Wb = (bf16*)ws;                                  // 4 MB
  bf16* hA = (bf16*)(ws + ((size_t)4 << 20));            // 8 MB
  bf16* hB = (bf16*)(ws + ((size_t)12 << 20));           // 8 MB
  unsigned* bar = (unsigned*)(ws + ((size_t)20 << 20));  // 4 B

  pack_w<<<2048, 256, 0, stream>>>(W, Wb);
  hipMemsetAsync(bar, 0, sizeof(unsigned), stream);

  int t0 = 0, t1 = T_N;
  void* args[] = { (void*)&x, (void*)&Wb, (void*)&bias, (void*)&hA, (void*)&hB,
                   (void*)&out, (void*)&bar, (void*)&t0, (void*)&t1 };
  hipError_t err = hipLaunchCooperativeKernel((const void*)rnn_fused, dim3(256),
                                              dim3(512), args, 0, stream);
  if (err != hipSuccess) {
    // fallback: per-step launches; barrier statically skipped (t0==t, t1==t+1)
    (void)hipGetLastError();
    for (int t = 0; t < T_N; ++t)
      rnn_fused<<<dim3(256), dim3(512), 0, stream>>>(x, Wb, bias, hA, hB, out,
                                                     bar, t, t + 1);
  }
}